// Round 7
// baseline (222.035 us; speedup 1.0000x reference)
//
#include <hip/hip_runtime.h>

// Problem constants (from setup_inputs): B=4, S=8, T=2048, R=256
#define T_N 2048
#define R_N 256
#define SLICES 32                     // B*S
#define NELEM (SLICES * T_N * R_N)    // 16,777,216 per tensor
#define INFV 3.0e38f
#define MIN_BLOCKS 2048               // 2048 x 256 threads, 8 float4/tensor/thread
#define MIN_THREADS (MIN_BLOCKS * 256)
#define LSTR 2056                     // list stride: 2048 + 8 sentinel slots

// Pair-preserving XOR bank swizzle (R2/R6-verified): logical word e ->
// e ^ ((e>>4)&30). Bit 0 preserved -> b64 pair access legal. Sentinels
// 2048..2055 map to themselves.
#define XS(e) ((e) ^ (((e) >> 4) & 30))

// DPP wave-64 min-reduce step (min is order-insensitive -> bit-safe).
#define DPPMIN(x, ctrl, rmask)                                                 \
    fminf((x), __int_as_float(__builtin_amdgcn_update_dpp(                     \
        0x7f800000, __float_as_int(x), (ctrl), (rmask), 0xf, false)))

// DPP wave-64 add step (VALU pipe; replaces ds_bpermute-based __shfl).
#define DPPADDF(x, ctrl, rmask)                                                \
    x += __int_as_float(__builtin_amdgcn_update_dpp(                           \
        0, __float_as_int(x), (ctrl), (rmask), 0xf, false))

// Wave-64 inclusive prefix sum; lane 63 ends with the wave total.
#define DPPSCAN(x)                                                             \
    do {                                                                       \
        DPPADDF(x, 0x111, 0xf);   /* row_shr:1  */                             \
        DPPADDF(x, 0x112, 0xf);   /* row_shr:2  */                             \
        DPPADDF(x, 0x114, 0xf);   /* row_shr:4  */                             \
        DPPADDF(x, 0x118, 0xf);   /* row_shr:8  */                             \
        DPPADDF(x, 0x142, 0xa);   /* row_bcast:15 -> rows 1,3 */               \
        DPPADDF(x, 0x143, 0xc);   /* row_bcast:31 -> rows 2,3 */               \
    } while (0)

// Deep-ILP streaming min (R2-verified two-half structure).
__global__ __launch_bounds__(256) void kmin(const float* __restrict__ x,
                                            const float* __restrict__ y,
                                            float* __restrict__ partial,
                                            float* __restrict__ out) {
    if (blockIdx.x == 0 && threadIdx.x < 4) out[threadIdx.x] = 0.0f;
    const int g0 = blockIdx.x * 256 + threadIdx.x;   // 0..524287
    const float4* __restrict__ x4 = (const float4*)x;
    const float4* __restrict__ y4 = (const float4*)y;
    float m0 = INFV, m1 = INFV;
    #pragma unroll
    for (int half = 0; half < 2; ++half) {
        float4 va[4], vb[4];
        #pragma unroll
        for (int it = 0; it < 4; ++it) {
            const int idx = g0 + (half * 4 + it) * MIN_THREADS;
            va[it] = x4[idx];
            vb[it] = y4[idx];
        }
        #pragma unroll
        for (int it = 0; it < 4; ++it) {
            m0 = fminf(m0, fminf(fminf(va[it].x, va[it].y), fminf(va[it].z, va[it].w)));
            m1 = fminf(m1, fminf(fminf(vb[it].x, vb[it].y), fminf(vb[it].z, vb[it].w)));
        }
    }
    float m = fminf(m0, m1);
    #pragma unroll
    for (int off = 32; off; off >>= 1) m = fminf(m, __shfl_down(m, off));
    __shared__ float sm[4];
    if ((threadIdx.x & 63) == 0) sm[threadIdx.x >> 6] = m;
    __syncthreads();
    if (threadIdx.x == 0)
        partial[blockIdx.x] = fminf(fminf(sm[0], sm[1]), fminf(sm[2], sm[3]));
}

// R7: 512-thread block = 2 problems, 4 waves/problem. LDS 33KB -> 4 blocks/CU
// (32 waves, 100% theoretical occupancy) vs R6's 2; finer barrier interleave.
// Unlike R1 (float2 = half-width uncoalesced VMEM, the real cause of its
// regression), staging keeps FULL float4 row loads: each thread reads the
// quad covering its block's col-pair and uses half; the sibling block reads
// the same line -> L2 absorbs the duplicate (remap co-schedules 8 siblings
// per 64B line on one XCD). Per-problem LDS/VALU issue counts and all
// order-sensitive arithmetic are identical to the R6-verified kernel.
__global__ __launch_bounds__(512, 8) void kmain(const float* __restrict__ x,
                                                const float* __restrict__ y,
                                                const float* __restrict__ partial,
                                                float* __restrict__ out) {
    __shared__ __align__(16) float L[4 * LSTR];  // p: U at (2p)*LSTR, V at (2p+1)*LSTR
    __shared__ float red8[8];
    __shared__ float psum[2][2][4];   // [problem][list][wave-chunk] scan partials
    __shared__ float pacc[2][4];      // [problem][wave] result partials

    const int tid = threadIdx.x;
    const int w = tid >> 6;           // wave 0..7
    const int lane = tid & 63;

    // ---- remap: 8 blocks sharing a 64B line (4 quads x 2 halves) -> same XCD
    const int blk = blockIdx.x;                    // 0..4095
    const int xcd = blk & 7;
    const int k2 = blk >> 3;
    const int sub = k2 & 7;                        // line sibling 0..7
    const int rest = k2 >> 3;                      // 0..63
    const int cp = (((rest & 1) << 3) + xcd) * 8 + sub;   // col-pair 0..127
    const int bs = rest >> 1;                              // 0..31
    const int cq = cp >> 1;                        // col-quad 0..63
    const int h  = cp & 1;                         // half within the float4
    const size_t base = (size_t)bs * (T_N * R_N) + (size_t)(cq * 4);

    // ---- issue ALL staging loads EARLY (independent of sh) ----
    float4 xa[2][2], ya[2][2];
    #pragma unroll
    for (int it = 0; it < 2; ++it) {
        const int r = (tid + 512 * it) << 1;       // rows r, r+1
        xa[it][0] = *(const float4*)(x + base + (size_t)r * R_N);
        xa[it][1] = *(const float4*)(x + base + (size_t)(r + 1) * R_N);
        ya[it][0] = *(const float4*)(y + base + (size_t)r * R_N);
        ya[it][1] = *(const float4*)(y + base + (size_t)(r + 1) * R_N);
    }

    // ---- phase 0: global min (partial[2048]) via DPP ----
    {
        float m = fminf(fminf(partial[tid], partial[tid + 512]),
                        fminf(partial[tid + 1024], partial[tid + 1536]));
        m = DPPMIN(m, 0x111, 0xf);    // row_shr:1
        m = DPPMIN(m, 0x112, 0xf);    // row_shr:2
        m = DPPMIN(m, 0x114, 0xf);    // row_shr:4
        m = DPPMIN(m, 0x118, 0xf);    // row_shr:8
        m = DPPMIN(m, 0x142, 0xa);    // row_bcast:15 -> rows 1,3
        m = DPPMIN(m, 0x143, 0xc);    // row_bcast:31 -> rows 2,3
        if (lane == 63) red8[w] = m;
    }
    // ---- sentinels: logical 2048..2055 (swizzle-identity) = INF ----
    if (tid < 32) L[(tid >> 3) * LSTR + T_N + (tid & 7)] = INFV;
    __syncthreads();
    float mn = red8[0];
    #pragma unroll
    for (int k = 1; k < 8; ++k) mn = fminf(mn, red8[k]);
    const float sh = 1.1f * fminf(mn, 0.0f);

    // ---- staging: b64 swizzled pair writes (rows 2st, 2st+1 per col) ----
    // h is block-uniform (SGPR) -> scalar branch, no divergence.
    #pragma unroll
    for (int it = 0; it < 2; ++it) {
        const int ws_ = XS((tid + 512 * it) << 1);
        if (h == 0) {
            L[0 * LSTR + ws_ + 0] = xa[it][0].x - sh;  L[0 * LSTR + ws_ + 1] = xa[it][1].x - sh;
            L[2 * LSTR + ws_ + 0] = xa[it][0].y - sh;  L[2 * LSTR + ws_ + 1] = xa[it][1].y - sh;
            L[1 * LSTR + ws_ + 0] = ya[it][0].x - sh;  L[1 * LSTR + ws_ + 1] = ya[it][1].x - sh;
            L[3 * LSTR + ws_ + 0] = ya[it][0].y - sh;  L[3 * LSTR + ws_ + 1] = ya[it][1].y - sh;
        } else {
            L[0 * LSTR + ws_ + 0] = xa[it][0].z - sh;  L[0 * LSTR + ws_ + 1] = xa[it][1].z - sh;
            L[2 * LSTR + ws_ + 0] = xa[it][0].w - sh;  L[2 * LSTR + ws_ + 1] = xa[it][1].w - sh;
            L[1 * LSTR + ws_ + 0] = ya[it][0].z - sh;  L[1 * LSTR + ws_ + 1] = ya[it][1].z - sh;
            L[3 * LSTR + ws_ + 0] = ya[it][0].w - sh;  L[3 * LSTR + ws_ + 1] = ya[it][1].w - sh;
        }
    }
    __syncthreads();

    const int p  = w >> 2;            // problem 0..1
    const int wl = w & 3;             // wave within problem
    const int pl = (wl << 6) | lane;  // problem-lane 0..255
    float* __restrict__ cu = &L[(2 * p) * LSTR];
    float* __restrict__ cv = &L[(2 * p + 1) * LSTR];

    // ---- scan: lane owns logical [8*pl, 8*pl+8), b64 pair access ----
    {
        int offp[4];
        #pragma unroll
        for (int c = 0; c < 4; ++c) offp[c] = XS(8 * pl + 2 * c);
        float uu[8], vv8[8];
        float su = 0.f, sv = 0.f;
        #pragma unroll
        for (int c = 0; c < 4; ++c) {
            const float2 t2 = *(const float2*)&cu[offp[c]];
            uu[2 * c] = t2.x; uu[2 * c + 1] = t2.y;
        }
        #pragma unroll
        for (int k = 0; k < 8; ++k) su += uu[k];
        #pragma unroll
        for (int c = 0; c < 4; ++c) {
            const float2 t2 = *(const float2*)&cv[offp[c]];
            vv8[2 * c] = t2.x; vv8[2 * c + 1] = t2.y;
        }
        #pragma unroll
        for (int k = 0; k < 8; ++k) sv += vv8[k];
        float iu = su, iv = sv;
        DPPSCAN(iu);
        DPPSCAN(iv);
        if (lane == 63) { psum[p][0][wl] = iu; psum[p][1][wl] = iv; }
        __syncthreads();
        float prefU = 0.f, totU = 0.f, prefV = 0.f, totV = 0.f;
        #pragma unroll
        for (int k = 0; k < 4; ++k) {
            const float a = psum[p][0][k], b = psum[p][1][k];
            totU += a; totV += b;
            if (k < wl) { prefU += a; prefV += b; }
        }
        const float invU = 1.0f / totU, invV = 1.0f / totV;
        float ru = prefU + (iu - su);
        float rv = prefV + (iv - sv);
        #pragma unroll
        for (int c = 0; c < 4; ++c) {
            const float ra = ru + uu[2 * c];
            const float rb = ra + uu[2 * c + 1];
            ru = rb;
            *(float2*)&cu[offp[c]] = make_float2(ra * invU, rb * invU);
        }
        #pragma unroll
        for (int c = 0; c < 4; ++c) {
            const float ra = rv + vv8[2 * c];
            const float rb = ra + vv8[2 * c + 1];
            rv = rb;
            *(float2*)&cv[offp[c]] = make_float2(ra * invV, rb * invV);
        }
    }
    __syncthreads();

    // ---- co-rank partition: lane handles merged window [16*pl, 16*pl+16) ----
    const int d = pl << 4;
    int i = 0, j = 0;
    if (d > 0) {
        int lo = (d > T_N) ? (d - T_N) : 0;
        int hi = (d < T_N) ? d : T_N;
        while (lo < hi) {
            const int mid = (lo + hi) >> 1;
            if (cu[XS(mid)] <= cv[XS(d - mid - 1)]) lo = mid + 1; else hi = mid;
        }
        i = lo; j = d - lo;
    }
    float qprev = 0.0f;
    if (d > 0) {
        const float pa_ = (i > 0) ? cu[XS(i - 1)] : -INFV;
        const float pb_ = (j > 0) ? cv[XS(j - 1)] : -INFV;
        qprev = fmaxf(pa_, pb_);
    }

    // ---- merge: 16 steps, refill only the advanced list, sentinel-direct ----
    float uv = cu[XS(i)];
    float vv = cv[XS(j)];
    float acc = 0.0f;
    #pragma unroll
    for (int s = 0; s < 16; ++s) {
        const bool take = (uv <= vv);
        const float q = fminf(uv, vv);
        const float dd = (float)(min(i, T_N - 1) - min(j, T_N - 1));
        acc += (q - qprev) * dd * dd;
        qprev = q;
        i += take ? 1 : 0;
        j += take ? 0 : 1;
        if (s < 15) {
            const int ni = take ? i : j;           // advanced index (<= 2048)
            const float* bp = take ? cu : cv;
            const float r = bp[XS(ni)];
            uv = take ? r : uv;
            vv = take ? vv : r;
        }
    }

    // ---- reduce: wave total via DPP (lane 63) -> LDS -> one atomic ----
    DPPSCAN(acc);
    if (lane == 63) pacc[p][wl] = acc;
    __syncthreads();
    if (tid == 0) {
        float r = 0.f;
        #pragma unroll
        for (int pp = 0; pp < 2; ++pp)
            r += (pacc[pp][0] + pacc[pp][1]) + (pacc[pp][2] + pacc[pp][3]);
        atomicAdd(&out[bs >> 3], r * (1.0f / ((float)T_N * (float)T_N)));
    }
}

extern "C" void kernel_launch(void* const* d_in, const int* in_sizes, int n_in,
                              void* d_out, int out_size, void* d_ws, size_t ws_size,
                              hipStream_t stream) {
    const float* x = (const float*)d_in[0];
    const float* y = (const float*)d_in[1];
    float* out = (float*)d_out;
    float* partial = (float*)d_ws;   // MIN_BLOCKS floats (8 KiB)

    kmin<<<MIN_BLOCKS, 256, 0, stream>>>(x, y, partial, out);
    kmain<<<SLICES * 128, 512, 0, stream>>>(x, y, partial, out);
}

// Round 8
// 198.855 us; speedup vs baseline: 1.1166x; 1.1166x over previous
//
#include <hip/hip_runtime.h>

// Problem constants (from setup_inputs): B=4, S=8, T=2048, R=256
#define T_N 2048
#define R_N 256
#define SLICES 32                     // B*S
#define NELEM (SLICES * T_N * R_N)    // 16,777,216 per tensor
#define INFV 3.0e38f
#define MIN_BLOCKS 2048               // 2048 x 256 threads, 8 float4/tensor/thread
#define MIN_THREADS (MIN_BLOCKS * 256)
#define LSTR 2056                     // list stride: 2048 + 8 sentinel slots

// Pair-preserving XOR bank swizzle (R2/R6-verified): logical word e ->
// e ^ ((e>>4)&30). Bit 0 preserved -> b64 pair access legal. Sentinels
// 2048..2055 map to themselves.
#define XS(e) ((e) ^ (((e) >> 4) & 30))

// DPP wave-64 min-reduce step (min is order-insensitive -> bit-safe).
#define DPPMIN(x, ctrl, rmask)                                                 \
    fminf((x), __int_as_float(__builtin_amdgcn_update_dpp(                     \
        0x7f800000, __float_as_int(x), (ctrl), (rmask), 0xf, false)))

// DPP wave-64 add step (VALU pipe; replaces ds_bpermute-based __shfl).
#define DPPADDF(x, ctrl, rmask)                                                \
    x += __int_as_float(__builtin_amdgcn_update_dpp(                           \
        0, __float_as_int(x), (ctrl), (rmask), 0xf, false))

// Wave-64 inclusive prefix sum; lane 63 ends with the wave total.
#define DPPSCAN(x)                                                             \
    do {                                                                       \
        DPPADDF(x, 0x111, 0xf);   /* row_shr:1  */                             \
        DPPADDF(x, 0x112, 0xf);   /* row_shr:2  */                             \
        DPPADDF(x, 0x114, 0xf);   /* row_shr:4  */                             \
        DPPADDF(x, 0x118, 0xf);   /* row_shr:8  */                             \
        DPPADDF(x, 0x142, 0xa);   /* row_bcast:15 -> rows 1,3 */               \
        DPPADDF(x, 0x143, 0xc);   /* row_bcast:31 -> rows 2,3 */               \
    } while (0)

// Deep-ILP streaming min (R2-verified two-half structure, unchanged).
__global__ __launch_bounds__(256) void kmin(const float* __restrict__ x,
                                            const float* __restrict__ y,
                                            float* __restrict__ partial,
                                            float* __restrict__ out) {
    if (blockIdx.x == 0 && threadIdx.x < 4) out[threadIdx.x] = 0.0f;
    const int g0 = blockIdx.x * 256 + threadIdx.x;   // 0..524287
    const float4* __restrict__ x4 = (const float4*)x;
    const float4* __restrict__ y4 = (const float4*)y;
    float m0 = INFV, m1 = INFV;
    #pragma unroll
    for (int half = 0; half < 2; ++half) {
        float4 va[4], vb[4];
        #pragma unroll
        for (int it = 0; it < 4; ++it) {
            const int idx = g0 + (half * 4 + it) * MIN_THREADS;
            va[it] = x4[idx];
            vb[it] = y4[idx];
        }
        #pragma unroll
        for (int it = 0; it < 4; ++it) {
            m0 = fminf(m0, fminf(fminf(va[it].x, va[it].y), fminf(va[it].z, va[it].w)));
            m1 = fminf(m1, fminf(fminf(vb[it].x, vb[it].y), fminf(vb[it].z, vb[it].w)));
        }
    }
    float m = fminf(m0, m1);
    #pragma unroll
    for (int off = 32; off; off >>= 1) m = fminf(m, __shfl_down(m, off));
    __shared__ float sm[4];
    if ((threadIdx.x & 63) == 0) sm[threadIdx.x >> 6] = m;
    __syncthreads();
    if (threadIdx.x == 0)
        partial[blockIdx.x] = fminf(fminf(sm[0], sm[1]), fminf(sm[2], sm[3]));
}

// 1024-thread block = 4 problems, 4 waves/problem (R6-verified structure).
// R8 (bit-exact vs R6): (a) staging writes RAW values; the -sh subtraction
// moves to the scan read (same op, same rounding -> identical cdf bits) so
// staging no longer depends on phase 0 and barrier(1) merges away;
// (b) phase 0 runs on wave 0 ONLY (64 lanes x 8 float4 = all 2048 partials,
// DPP min, one LDS scalar) -- the other 15 waves skip it entirely.
// Scan/corank/merge/reduce byte-identical to R6.
__global__ __launch_bounds__(1024, 8) void kmain(const float* __restrict__ x,
                                                 const float* __restrict__ y,
                                                 const float* __restrict__ partial,
                                                 float* __restrict__ out) {
    __shared__ __align__(16) float L[8 * LSTR];  // problem p: U at (2p)*LSTR, V at (2p+1)*LSTR
    __shared__ float redmn;           // block-wide global min (written by wave 0)
    __shared__ float psum[4][2][4];   // [problem][list][wave-chunk] scan partials
    __shared__ float pacc[4][4];      // [problem][wave] result partials

    const int tid = threadIdx.x;
    const int w = tid >> 6;           // wave 0..15
    const int lane = tid & 63;

    // ---- XCD-aware remap: 4 blocks sharing a 64B global line -> same XCD ----
    const int blk = blockIdx.x;
    const int xcd = blk & 7;
    const int k2 = blk >> 3;
    const int sub = k2 & 3;
    const int rest = k2 >> 2;
    const int rt = (((rest & 1) << 3) + xcd) * 4 + sub;   // 0..63
    const int bs = rest >> 1;                              // 0..31
    const size_t base = (size_t)bs * (T_N * R_N) + (size_t)(rt * 4);

    // ---- staging loads (no dependency on sh now): rows 2tid, 2tid+1 ----
    const int r0 = tid << 1;
    const float4 a0 = *(const float4*)(x + base + (size_t)r0 * R_N);
    const float4 a1 = *(const float4*)(x + base + (size_t)(r0 + 1) * R_N);
    const float4 b0 = *(const float4*)(y + base + (size_t)r0 * R_N);
    const float4 b1 = *(const float4*)(y + base + (size_t)(r0 + 1) * R_N);

    // ---- phase 0 (wave 0 only): global min of partial[2048] ----
    if (w == 0) {
        const float4* __restrict__ p4 = (const float4*)partial;
        float m = INFV;
        #pragma unroll
        for (int k = 0; k < 8; ++k) {
            const float4 t = p4[lane + 64 * k];   // coalesced, covers all 512 quads
            m = fminf(m, fminf(fminf(t.x, t.y), fminf(t.z, t.w)));
        }
        m = DPPMIN(m, 0x111, 0xf);    // row_shr:1
        m = DPPMIN(m, 0x112, 0xf);    // row_shr:2
        m = DPPMIN(m, 0x114, 0xf);    // row_shr:4
        m = DPPMIN(m, 0x118, 0xf);    // row_shr:8
        m = DPPMIN(m, 0x142, 0xa);    // row_bcast:15 -> rows 1,3
        m = DPPMIN(m, 0x143, 0xc);    // row_bcast:31 -> rows 2,3
        if (lane == 63) redmn = m;
    }

    // ---- sentinels: logical 2048..2055 (swizzle-identity) = INF ----
    if (tid < 64) L[(tid >> 3) * LSTR + T_N + (tid & 7)] = INFV;

    // ---- staging: b64 swizzled pair writes of RAW values ----
    {
        const int ws_ = XS(r0);       // even -> 8B-aligned
        *(float2*)&L[0 * LSTR + ws_] = make_float2(a0.x, a1.x);
        *(float2*)&L[2 * LSTR + ws_] = make_float2(a0.y, a1.y);
        *(float2*)&L[4 * LSTR + ws_] = make_float2(a0.z, a1.z);
        *(float2*)&L[6 * LSTR + ws_] = make_float2(a0.w, a1.w);
        *(float2*)&L[1 * LSTR + ws_] = make_float2(b0.x, b1.x);
        *(float2*)&L[3 * LSTR + ws_] = make_float2(b0.y, b1.y);
        *(float2*)&L[5 * LSTR + ws_] = make_float2(b0.z, b1.z);
        *(float2*)&L[7 * LSTR + ws_] = make_float2(b0.w, b1.w);
    }
    __syncthreads();                  // covers staging + redmn

    const float sh = 1.1f * fminf(redmn, 0.0f);

    const int p  = w >> 2;            // problem 0..3
    const int wl = w & 3;             // wave within problem
    const int pl = (wl << 6) | lane;  // problem-lane 0..255
    float* __restrict__ cu = &L[(2 * p) * LSTR];
    float* __restrict__ cv = &L[(2 * p + 1) * LSTR];

    // ---- scan: lane owns logical [8*pl, 8*pl+8), b64 pair access ----
    // -sh applied here (same op/rounding as R6's staging-time subtract).
    {
        int offp[4];
        #pragma unroll
        for (int c = 0; c < 4; ++c) offp[c] = XS(8 * pl + 2 * c);
        float uu[8], vv8[8];
        float su = 0.f, sv = 0.f;
        #pragma unroll
        for (int c = 0; c < 4; ++c) {
            const float2 t2 = *(const float2*)&cu[offp[c]];
            uu[2 * c] = t2.x - sh; uu[2 * c + 1] = t2.y - sh;
        }
        #pragma unroll
        for (int k = 0; k < 8; ++k) su += uu[k];
        #pragma unroll
        for (int c = 0; c < 4; ++c) {
            const float2 t2 = *(const float2*)&cv[offp[c]];
            vv8[2 * c] = t2.x - sh; vv8[2 * c + 1] = t2.y - sh;
        }
        #pragma unroll
        for (int k = 0; k < 8; ++k) sv += vv8[k];
        float iu = su, iv = sv;
        DPPSCAN(iu);
        DPPSCAN(iv);
        if (lane == 63) { psum[p][0][wl] = iu; psum[p][1][wl] = iv; }
        __syncthreads();
        float prefU = 0.f, totU = 0.f, prefV = 0.f, totV = 0.f;
        #pragma unroll
        for (int k = 0; k < 4; ++k) {
            const float a = psum[p][0][k], b = psum[p][1][k];
            totU += a; totV += b;
            if (k < wl) { prefU += a; prefV += b; }
        }
        const float invU = 1.0f / totU, invV = 1.0f / totV;
        float ru = prefU + (iu - su);
        float rv = prefV + (iv - sv);
        #pragma unroll
        for (int c = 0; c < 4; ++c) {
            const float ra = ru + uu[2 * c];
            const float rb = ra + uu[2 * c + 1];
            ru = rb;
            *(float2*)&cu[offp[c]] = make_float2(ra * invU, rb * invU);
        }
        #pragma unroll
        for (int c = 0; c < 4; ++c) {
            const float ra = rv + vv8[2 * c];
            const float rb = ra + vv8[2 * c + 1];
            rv = rb;
            *(float2*)&cv[offp[c]] = make_float2(ra * invV, rb * invV);
        }
    }
    __syncthreads();

    // ---- co-rank partition: lane handles merged window [16*pl, 16*pl+16) ----
    const int d = pl << 4;
    int i = 0, j = 0;
    if (d > 0) {
        int lo = (d > T_N) ? (d - T_N) : 0;
        int hi = (d < T_N) ? d : T_N;
        while (lo < hi) {
            const int mid = (lo + hi) >> 1;
            if (cu[XS(mid)] <= cv[XS(d - mid - 1)]) lo = mid + 1; else hi = mid;
        }
        i = lo; j = d - lo;
    }
    float qprev = 0.0f;
    if (d > 0) {
        const float pa_ = (i > 0) ? cu[XS(i - 1)] : -INFV;
        const float pb_ = (j > 0) ? cv[XS(j - 1)] : -INFV;
        qprev = fmaxf(pa_, pb_);
    }

    // ---- merge: 16 steps, refill only the advanced list, sentinel-direct ----
    float uv = cu[XS(i)];
    float vv = cv[XS(j)];
    float acc = 0.0f;
    #pragma unroll
    for (int s = 0; s < 16; ++s) {
        const bool take = (uv <= vv);
        const float q = fminf(uv, vv);
        const float dd = (float)(min(i, T_N - 1) - min(j, T_N - 1));
        acc += (q - qprev) * dd * dd;
        qprev = q;
        i += take ? 1 : 0;
        j += take ? 0 : 1;
        if (s < 15) {
            const int ni = take ? i : j;           // advanced index (<= 2048)
            const float* bp = take ? cu : cv;
            const float r = bp[XS(ni)];
            uv = take ? r : uv;
            vv = take ? vv : r;
        }
    }

    // ---- reduce: wave total via DPP (lane 63) -> LDS -> one atomic ----
    DPPSCAN(acc);
    if (lane == 63) pacc[p][wl] = acc;
    __syncthreads();
    if (tid == 0) {
        float r = 0.f;
        #pragma unroll
        for (int pp = 0; pp < 4; ++pp)
            r += (pacc[pp][0] + pacc[pp][1]) + (pacc[pp][2] + pacc[pp][3]);
        atomicAdd(&out[bs >> 3], r * (1.0f / ((float)T_N * (float)T_N)));
    }
}

extern "C" void kernel_launch(void* const* d_in, const int* in_sizes, int n_in,
                              void* d_out, int out_size, void* d_ws, size_t ws_size,
                              hipStream_t stream) {
    const float* x = (const float*)d_in[0];
    const float* y = (const float*)d_in[1];
    float* out = (float*)d_out;
    float* partial = (float*)d_ws;   // MIN_BLOCKS floats (8 KiB)

    kmin<<<MIN_BLOCKS, 256, 0, stream>>>(x, y, partial, out);
    kmain<<<SLICES * 64, 1024, 0, stream>>>(x, y, partial, out);
}